// Round 12
// baseline (199.337 us; speedup 1.0000x reference)
//
#include <hip/hip_runtime.h>
#include <hip/hip_bf16.h>
#include <stdint.h>

#define Bc 4
#define Sc 2048
#define Dc 1024
#define Hc 16
#define HDc 64
#define LOG2E 1.44269504088896f

typedef __attribute__((ext_vector_type(8))) __bf16 bf16x8;
typedef __attribute__((ext_vector_type(4))) __bf16 bf16x4;
typedef __attribute__((ext_vector_type(4))) float f32x4;
typedef __attribute__((ext_vector_type(16))) float f32x16;
typedef __attribute__((ext_vector_type(2))) int i32x2_t;

__device__ __forceinline__ f32x4 mfma16(bf16x8 a, bf16x8 b, f32x4 c) {
  return __builtin_amdgcn_mfma_f32_16x16x32_bf16(a, b, c, 0, 0, 0);
}
__device__ __forceinline__ f32x16 mfma32(bf16x8 a, bf16x8 b, f32x16 c) {
  return __builtin_amdgcn_mfma_f32_32x32x16_bf16(a, b, c, 0, 0, 0);
}
__device__ __forceinline__ uint32_t cvtpk_bf16(float lo, float hi) {
  uint32_t r;
  asm("v_cvt_pk_bf16_f32 %0, %1, %2" : "=v"(r) : "v"(lo), "v"(hi));
  return r;
}
__device__ __forceinline__ void gload_lds16(const void* g, void* l) {
  __builtin_amdgcn_global_load_lds(
      (const __attribute__((address_space(1))) void*)g,
      (__attribute__((address_space(3))) void*)l, 16, 0, 0);
}
__device__ __forceinline__ void gload_lds4(const void* g, void* l) {
  __builtin_amdgcn_global_load_lds(
      (const __attribute__((address_space(1))) void*)g,
      (__attribute__((address_space(3))) void*)l, 4, 0, 0);
}

// ---------------- Kernel 0a: mask * log2e ----------------
__global__ __launch_bounds__(256) void maskscale_kernel(const float* __restrict__ m,
                                                        float* __restrict__ mkx) {
  const int i = blockIdx.x * 256 + threadIdx.x;  // 8192 total
  mkx[i] = m[i] * LOG2E;
}

// ---------------- Kernel 0b: hs (fp32) -> bf16 ----------------
__global__ __launch_bounds__(256) void hs2bf_kernel(const float* __restrict__ hs,
                                                    __bf16* __restrict__ Ah) {
  const size_t i = ((size_t)blockIdx.x * 256 + threadIdx.x) * 8;
  float4 f0 = *(const float4*)(hs + i);
  float4 f1 = *(const float4*)(hs + i + 4);
  bf16x8 o;
  o[0] = (__bf16)f0.x; o[1] = (__bf16)f0.y; o[2] = (__bf16)f0.z; o[3] = (__bf16)f0.w;
  o[4] = (__bf16)f1.x; o[5] = (__bf16)f1.y; o[6] = (__bf16)f1.z; o[7] = (__bf16)f1.w;
  *(bf16x8*)(Ah + i) = o;
}

// ---------------- Kernel 1: Wt[w][n][k] = (bf16) W[w][k][n] ----------------
__global__ __launch_bounds__(256) void wtrans_kernel(
    const float* __restrict__ Wq, const float* __restrict__ Wk,
    const float* __restrict__ Wv, __bf16* __restrict__ Wt) {
  const float* W = (blockIdx.z == 0) ? Wq : (blockIdx.z == 1 ? Wk : Wv);
  __bf16* out = Wt + (size_t)blockIdx.z * Dc * Dc;
  const int n0 = blockIdx.x * 64, k0 = blockIdx.y * 64;
  __shared__ float tile[64][65];
  const int tid = threadIdx.x;
  const int r = tid >> 2, cs = (tid & 3) * 16;
  const float* src = W + (size_t)(k0 + r) * Dc + n0 + cs;
  float4 f0 = *(const float4*)(src + 0);
  float4 f1 = *(const float4*)(src + 4);
  float4 f2 = *(const float4*)(src + 8);
  float4 f3 = *(const float4*)(src + 12);
#pragma unroll
  for (int j = 0; j < 4; ++j) {
    tile[r][cs + j] = ((const float*)&f0)[j];
    tile[r][cs + 4 + j] = ((const float*)&f1)[j];
    tile[r][cs + 8 + j] = ((const float*)&f2)[j];
    tile[r][cs + 12 + j] = ((const float*)&f3)[j];
  }
  __syncthreads();
  bf16x8 o0, o1;
#pragma unroll
  for (int j = 0; j < 8; ++j) {
    o0[j] = (__bf16)tile[cs + j][r];
    o1[j] = (__bf16)tile[cs + 8 + j][r];
  }
  __bf16* dst = out + (size_t)(n0 + r) * Dc + k0 + cs;
  *(bf16x8*)(dst) = o0;
  *(bf16x8*)(dst + 8) = o1;
}

// ---------------- Kernel 2: fused QKV GEMM (unchanged from R11) ------------
__global__ __launch_bounds__(512) void qkv_gemm_kernel(
    const __bf16* __restrict__ A, const __bf16* __restrict__ Wt,
    const float* __restrict__ bq, const float* __restrict__ bk,
    const float* __restrict__ bv,
    __bf16* __restrict__ Qo, __bf16* __restrict__ Kf, __bf16* __restrict__ Vf) {
  const int wg = (blockIdx.x & 7) * 96 + (blockIdx.x >> 3);
  const int nn = wg >> 6;            // 0..11 (256-col panel)
  const int mm = wg & 63;            // 0..63 (128-row panel)
  const int m0 = mm * 128;
  const int n0 = nn * 256;           // global col in [0,3072)
  const int w = n0 >> 10;            // 0=Q,1=K,2=V
  const int nbase = n0 & 1023;

  const float* bias = (w == 0) ? bq : (w == 1 ? bk : bv);

  __shared__ __attribute__((aligned(16))) __bf16 Asm[3][4096];   // 128x32
  __shared__ __attribute__((aligned(16))) __bf16 Bsm[3][8192];   // 256x32

  const int tid = threadIdx.x, lane = tid & 63, wid = tid >> 6;
  const int wr = wid >> 2, wc = wid & 3;   // 2M x 4N waves
  const int lg = lane >> 4, li = lane & 15;

  f32x4 acc[4][4] = {};

  auto stage = [&](int buf, int kt) {
    const int k0 = kt * 32;
    {
      const int row = tid >> 2;
      const int sc = (tid & 3) ^ (row & 3);
      gload_lds16(A + (size_t)(m0 + row) * Dc + k0 + sc * 8,
                  &Asm[buf][wid * 512]);
    }
#pragma unroll
    for (int p = 0; p < 2; ++p) {
      const int row = p * 128 + (tid >> 2);
      const int sc = (tid & 3) ^ (row & 3);
      gload_lds16(Wt + (size_t)(n0 + row) * Dc + k0 + sc * 8,
                  &Bsm[buf][p * 4096 + wid * 512]);
    }
  };

  const int aoff = (wr * 64 + li) * 32 + ((lg ^ (li & 3)) * 8);
  const int boff = (wc * 64 + li) * 32 + ((lg ^ (li & 3)) * 8);

  stage(0, 0);
  stage(1, 1);
  for (int ks = 0; ks < 32; ++ks) {
    asm volatile("s_waitcnt vmcnt(3)" ::: "memory");  // tile ks landed
    __builtin_amdgcn_sched_barrier(0);
    __builtin_amdgcn_s_barrier();
    __builtin_amdgcn_sched_barrier(0);
    {
      const int tn = (ks + 2 < 32) ? ks + 2 : 31;
      stage((ks + 2) % 3, tn);
    }
    const __bf16* Ab = &Asm[ks % 3][0] + aoff;
    const __bf16* Bb = &Bsm[ks % 3][0] + boff;
    bf16x8 af[4], bfr[4];
#pragma unroll
    for (int i = 0; i < 4; ++i) af[i] = *(const bf16x8*)(Ab + i * 512);
#pragma unroll
    for (int j = 0; j < 4; ++j) bfr[j] = *(const bf16x8*)(Bb + j * 512);
    __builtin_amdgcn_s_setprio(1);
#pragma unroll
    for (int i = 0; i < 4; ++i)
#pragma unroll
      for (int j = 0; j < 4; ++j)
        acc[i][j] = mfma16(af[i], bfr[j], acc[i][j]);
    __builtin_amdgcn_s_setprio(0);
  }

  if (w == 0) {
    const float scl = 0.125f * LOG2E;
#pragma unroll
    for (int i = 0; i < 4; ++i) {
#pragma unroll
      for (int j = 0; j < 4; ++j) {
        const int n = nbase + wc * 64 + j * 16 + li;
        const float bb = bias[n];
        const int h = n >> 6, hd = n & 63;
#pragma unroll
        for (int r = 0; r < 4; ++r) {
          const int m = m0 + wr * 64 + i * 16 + lg * 4 + r;
          const int b = m >> 11, s = m & 2047;
          Qo[(((size_t)b * Hc + h) * Sc + s) * HDc + hd] =
              (__bf16)((acc[i][j][r] + bb) * scl);
        }
      }
    }
  } else if (w == 1) {
#pragma unroll
    for (int j = 0; j < 4; ++j) {
      const int n = nbase + wc * 64 + j * 16 + li;
      const float bb = bias[n];
      const int h = n >> 6, hd = n & 63;
      const int c = hd >> 4, shi = (hd >> 3) & 1, j8 = hd & 7;
#pragma unroll
      for (int i = 0; i < 4; ++i) {
#pragma unroll
        for (int r = 0; r < 4; ++r) {
          const int m = m0 + wr * 64 + i * 16 + lg * 4 + r;
          const int b = m >> 11, s = m & 2047;
          const int bh = b * Hc + h;
          const int t = s >> 6, kt = s & 63;
          const int slot = (kt >> 5) * 256 + c * 64 + shi * 32 + (kt & 31);
          Kf[((size_t)(bh * 32 + t)) * 4096 + slot * 8 + j8] =
              (__bf16)(acc[i][j][r] + bb);
        }
      }
    }
  } else {
#pragma unroll
    for (int i = 0; i < 4; ++i) {
      const int mbase = m0 + wr * 64 + i * 16 + lg * 4;
      const int b = mbase >> 11, sk = mbase & 2047;
      const int t = sk >> 6, kt = sk & 63;
      const int kc = kt >> 4, shi = (kt >> 3) & 1, j0 = kt & 7;  // j0 in {0,4}
#pragma unroll
      for (int j = 0; j < 4; ++j) {
        const int n = nbase + wc * 64 + j * 16 + li;
        const float bb = bias[n];
        const int h = n >> 6, hd = n & 63;
        const int nb = hd >> 5, sqr = hd & 31;
        const int bh = b * Hc + h;
        const int slot = kc * 128 + nb * 64 + shi * 32 + sqr;
        bf16x4 o;
#pragma unroll
        for (int r = 0; r < 4; ++r) o[r] = (__bf16)(acc[i][j][r] + bb);
        *(bf16x4*)&Vf[((size_t)(bh * 32 + t)) * 4096 + slot * 8 + j0] = o;
      }
    }
  }
}

// ---------------- Kernel 3: attention (2 q-sets/wave, 4-wave blocks) -------
// Each wave owns 64 q-rows (set A at q0, set B at q0+128): every K/V fragment
// read from LDS feeds TWO mfmas -> per-CU ds_read_b128 traffic halves (the
// R11 bottleneck: 16 reads x 8 waves x 2 blk x 32 t x 12cyc = 41us/CU).
// 4 waves/block (256 thr, 256 q-rows), grid 512 -> 2 blocks/CU. 3 LDS bufs,
// 1-ahead: {vmcnt(5); barrier; stage(t+2); qkAB(t); packAB; PV(t)}.
// No cross-tile sacc ping-pong (VGPR budget); A/B pair provides MFMA||VALU
// overlap within the iter. Mask C-init is key-only -> shared by both sets.
__global__ __launch_bounds__(256) void attn_kernel(
    const __bf16* __restrict__ Q, const __bf16* __restrict__ Kf,
    const __bf16* __restrict__ Vf, const float* __restrict__ mkx,
    float* __restrict__ out) {
  const int idx = blockIdx.x;            // 0..511
  const int bh = (idx & 7) * 8 + ((idx >> 3) & 7);  // bh's 8 blocks same XCD
  const int qt = idx >> 6;               // 0..7
  const int b = bh >> 4, h = bh & 15;
  const __bf16* qb = Q + (size_t)bh * Sc * HDc;
  const __bf16* kfb = Kf + (size_t)bh * 32 * 4096;
  const __bf16* vfb = Vf + (size_t)bh * 32 * 4096;
  const float* mb = mkx + (size_t)b * Sc;

  const int tid = threadIdx.x, lane = tid & 63, wid = tid >> 6;  // wid 0..3
  const int hi = lane >> 5, qr = lane & 31;

  __shared__ __attribute__((aligned(16))) __bf16 Ksm[3][4096];
  __shared__ __attribute__((aligned(16))) __bf16 Vsm[3][4096];
  __shared__ __attribute__((aligned(16))) float Msm[3][64];

  const int q0 = qt * 256 + wid * 32;    // set A rows; set B = q0 + 128

  bf16x8 qfA[4], qfB[4];
#pragma unroll
  for (int c = 0; c < 4; ++c) {
    qfA[c] = *(const bf16x8*)(qb + (size_t)(q0 + qr) * HDc + c * 16 + hi * 8);
    qfB[c] = *(const bf16x8*)(qb + (size_t)(q0 + 128 + qr) * HDc + c * 16 + hi * 8);
  }

  bf16x8 onesv;
#pragma unroll
  for (int j = 0; j < 8; ++j) onesv[j] = (__bf16)1.0f;

  f32x16 oaccA[2] = {}, oaccB[2] = {};
  f32x16 laccA = {}, laccB = {};

  // exactly 5 vmem ops per wave per stage (2 K + 2 V + 1 mask)
  auto stage = [&](int buf, int t) {
    const size_t tb = (size_t)t * 4096;
#pragma unroll
    for (int p = 0; p < 2; ++p) {
      gload_lds16(kfb + tb + p * 2048 + (size_t)tid * 8,
                  &Ksm[buf][p * 2048 + wid * 512]);
      gload_lds16(vfb + tb + p * 2048 + (size_t)tid * 8,
                  &Vsm[buf][p * 2048 + wid * 512]);
    }
    gload_lds4(mb + t * 64 + lane, &Msm[buf][0]);
  };

  // full body for one tile: QK both sets, exp/pack both, PV both
  auto body = [&](int buf) {
    const __bf16* Kb = &Ksm[buf][0] + lane * 8;
    const __bf16* Vb = &Vsm[buf][0] + lane * 8;
    const float* Mb = &Msm[buf][0];
    f32x16 sa[2], sb2[2];
#pragma unroll
    for (int kb2 = 0; kb2 < 2; ++kb2) {
#pragma unroll
      for (int g = 0; g < 4; ++g) {
        const float4 m4 = *(const float4*)&Mb[kb2 * 32 + g * 8 + hi * 4];
#pragma unroll
        for (int e = 0; e < 4; ++e) {
          sa[kb2][g * 4 + e] = ((const float*)&m4)[e];
          sb2[kb2][g * 4 + e] = ((const float*)&m4)[e];
        }
      }
    }
    __builtin_amdgcn_s_setprio(1);
#pragma unroll
    for (int kb2 = 0; kb2 < 2; ++kb2) {
#pragma unroll
      for (int c = 0; c < 4; ++c) {
        const bf16x8 kf = *(const bf16x8*)(Kb + (kb2 * 4 + c) * 512);
        sa[kb2] = mfma32(kf, qfA[c], sa[kb2]);
        sb2[kb2] = mfma32(kf, qfB[c], sb2[kb2]);
      }
    }
    __builtin_amdgcn_s_setprio(0);

    bf16x8 paA[4], paB[4];
#pragma unroll
    for (int set = 0; set < 2; ++set) {
      f32x16* s = (set == 0) ? sa : sb2;
      bf16x8* pa = (set == 0) ? paA : paB;
#pragma unroll
      for (int kb2 = 0; kb2 < 2; ++kb2) {
        uint32_t wv[8];
#pragma unroll
        for (int j = 0; j < 8; ++j)
          wv[j] = cvtpk_bf16(__builtin_amdgcn_exp2f(s[kb2][2 * j]),
                             __builtin_amdgcn_exp2f(s[kb2][2 * j + 1]));
#pragma unroll
        for (int cc = 0; cc < 2; ++cc) {
          i32x2_t s02 = __builtin_amdgcn_permlane32_swap(
              (int)wv[cc * 4 + 0], (int)wv[cc * 4 + 2], false, false);
          i32x2_t s13 = __builtin_amdgcn_permlane32_swap(
              (int)wv[cc * 4 + 1], (int)wv[cc * 4 + 3], false, false);
          union { uint32_t u[4]; bf16x8 v; } af;
          af.u[0] = (uint32_t)s02[0];
          af.u[1] = (uint32_t)s13[0];
          af.u[2] = (uint32_t)s02[1];
          af.u[3] = (uint32_t)s13[1];
          pa[kb2 * 2 + cc] = af.v;
        }
      }
    }

    __builtin_amdgcn_s_setprio(1);
#pragma unroll
    for (int kc = 0; kc < 4; ++kc) {
      laccA = mfma32(paA[kc], onesv, laccA);
      laccB = mfma32(paB[kc], onesv, laccB);
#pragma unroll
      for (int nb = 0; nb < 2; ++nb) {
        const bf16x8 vf = *(const bf16x8*)(Vb + (kc * 2 + nb) * 512);
        oaccA[nb] = mfma32(paA[kc], vf, oaccA[nb]);
        oaccB[nb] = mfma32(paB[kc], vf, oaccB[nb]);
      }
    }
    __builtin_amdgcn_s_setprio(0);
  };

  const int NT = Sc / 64;  // 32

  stage(0, 0);
  stage(1, 1);

  // iter t: {vmcnt(5) [stage(t) done, stage(t+1) in flight]; barrier;
  //          stage(t+2 -> (t+2)%3); body(t%3)}
#define ITER(T, PB, SB)                                                 \
  {                                                                     \
    const int t_ = (T);                                                 \
    const int tn_ = (t_ + 2 < NT) ? t_ + 2 : NT - 1;                    \
    asm volatile("s_waitcnt vmcnt(5)" ::: "memory");                    \
    __builtin_amdgcn_sched_barrier(0);                                  \
    __builtin_amdgcn_s_barrier();                                       \
    __builtin_amdgcn_sched_barrier(0);                                  \
    stage(SB, tn_);                                                     \
    body(PB);                                                           \
  }

  for (int t3 = 0; t3 < 30; t3 += 3) {
    ITER(t3 + 0, 0, 2);
    ITER(t3 + 1, 1, 0);
    ITER(t3 + 2, 2, 1);
  }
  ITER(30, 0, 2);
  ITER(31, 1, 0);
#undef ITER

  // normalize + store both sets
  float invA[16], invB[16];
#pragma unroll
  for (int r = 0; r < 16; ++r) {
    invA[r] = __builtin_amdgcn_rcpf(laccA[r]);
    invB[r] = __builtin_amdgcn_rcpf(laccB[r]);
  }
#pragma unroll
  for (int nb = 0; nb < 2; ++nb) {
#pragma unroll
    for (int r = 0; r < 16; ++r) {
      const int row = (r & 3) + 8 * (r >> 2) + 4 * hi;
      out[((size_t)b * Sc + q0 + row) * Dc + h * HDc + nb * 32 + qr] =
          oaccA[nb][r] * invA[r];
      out[((size_t)b * Sc + q0 + 128 + row) * Dc + h * HDc + nb * 32 + qr] =
          oaccB[nb][r] * invB[r];
    }
  }
}

// ---------------- launch ----------------
extern "C" void kernel_launch(void* const* d_in, const int* in_sizes, int n_in,
                              void* d_out, int out_size, void* d_ws,
                              size_t ws_size, hipStream_t stream) {
  const float* hs = (const float*)d_in[0];
  const float* mask = (const float*)d_in[1];
  const float* Wq = (const float*)d_in[2];
  const float* bq = (const float*)d_in[3];
  const float* Wk = (const float*)d_in[4];
  const float* bk = (const float*)d_in[5];
  const float* Wv = (const float*)d_in[6];
  const float* bv = (const float*)d_in[7];
  float* out = (float*)d_out;

  char* ws = (char*)d_ws;
  const size_t qkv_bytes = (size_t)Bc * Hc * Sc * HDc * 2;  // 16.78 MB
  __bf16* Wt = (__bf16*)ws;                                 // 6 MB
  __bf16* Ah = (__bf16*)(ws + 6291456);
  __bf16* Q = (__bf16*)(ws + 6291456 + qkv_bytes);
  __bf16* Kf = (__bf16*)(ws + 6291456 + 2 * qkv_bytes);
  __bf16* Vf = (__bf16*)(ws + 6291456 + 3 * qkv_bytes);
  float* mkx = (float*)(ws + 6291456 + 4 * qkv_bytes);      // 32 KB

  maskscale_kernel<<<32, 256, 0, stream>>>(mask, mkx);
  hs2bf_kernel<<<4096, 256, 0, stream>>>(hs, Ah);
  wtrans_kernel<<<dim3(16, 16, 3), 256, 0, stream>>>(Wq, Wk, Wv, Wt);
  qkv_gemm_kernel<<<768, 512, 0, stream>>>(Ah, Wt, bq, bk, bv, Q, Kf, Vf);
  attn_kernel<<<512, 256, 0, stream>>>(Q, Kf, Vf, mkx, out);
}

// Round 13
// 197.103 us; speedup vs baseline: 1.0113x; 1.0113x over previous
//
#include <hip/hip_runtime.h>
#include <hip/hip_bf16.h>
#include <stdint.h>

#define Bc 4
#define Sc 2048
#define Dc 1024
#define Hc 16
#define HDc 64
#define LOG2E 1.44269504088896f

typedef __attribute__((ext_vector_type(8))) __bf16 bf16x8;
typedef __attribute__((ext_vector_type(4))) __bf16 bf16x4;
typedef __attribute__((ext_vector_type(4))) float f32x4;
typedef __attribute__((ext_vector_type(16))) float f32x16;
typedef __attribute__((ext_vector_type(2))) int i32x2_t;

__device__ __forceinline__ f32x4 mfma16(bf16x8 a, bf16x8 b, f32x4 c) {
  return __builtin_amdgcn_mfma_f32_16x16x32_bf16(a, b, c, 0, 0, 0);
}
__device__ __forceinline__ f32x16 mfma32(bf16x8 a, bf16x8 b, f32x16 c) {
  return __builtin_amdgcn_mfma_f32_32x32x16_bf16(a, b, c, 0, 0, 0);
}
__device__ __forceinline__ uint32_t cvtpk_bf16(float lo, float hi) {
  uint32_t r;
  asm("v_cvt_pk_bf16_f32 %0, %1, %2" : "=v"(r) : "v"(lo), "v"(hi));
  return r;
}
__device__ __forceinline__ void gload_lds16(const void* g, void* l) {
  __builtin_amdgcn_global_load_lds(
      (const __attribute__((address_space(1))) void*)g,
      (__attribute__((address_space(3))) void*)l, 16, 0, 0);
}
__device__ __forceinline__ void gload_lds4(const void* g, void* l) {
  __builtin_amdgcn_global_load_lds(
      (const __attribute__((address_space(1))) void*)g,
      (__attribute__((address_space(3))) void*)l, 4, 0, 0);
}

// ---------------- Kernel 0a: mask * log2e ----------------
__global__ __launch_bounds__(256) void maskscale_kernel(const float* __restrict__ m,
                                                        float* __restrict__ mkx) {
  const int i = blockIdx.x * 256 + threadIdx.x;  // 8192 total
  mkx[i] = m[i] * LOG2E;
}

// ---------------- Kernel 0b: hs (fp32) -> bf16 ----------------
__global__ __launch_bounds__(256) void hs2bf_kernel(const float* __restrict__ hs,
                                                    __bf16* __restrict__ Ah) {
  const size_t i = ((size_t)blockIdx.x * 256 + threadIdx.x) * 8;
  float4 f0 = *(const float4*)(hs + i);
  float4 f1 = *(const float4*)(hs + i + 4);
  bf16x8 o;
  o[0] = (__bf16)f0.x; o[1] = (__bf16)f0.y; o[2] = (__bf16)f0.z; o[3] = (__bf16)f0.w;
  o[4] = (__bf16)f1.x; o[5] = (__bf16)f1.y; o[6] = (__bf16)f1.z; o[7] = (__bf16)f1.w;
  *(bf16x8*)(Ah + i) = o;
}

// ---------------- Kernel 1: Wt[w][n][k] = (bf16) W[w][k][n] ----------------
__global__ __launch_bounds__(256) void wtrans_kernel(
    const float* __restrict__ Wq, const float* __restrict__ Wk,
    const float* __restrict__ Wv, __bf16* __restrict__ Wt) {
  const float* W = (blockIdx.z == 0) ? Wq : (blockIdx.z == 1 ? Wk : Wv);
  __bf16* out = Wt + (size_t)blockIdx.z * Dc * Dc;
  const int n0 = blockIdx.x * 64, k0 = blockIdx.y * 64;
  __shared__ float tile[64][65];
  const int tid = threadIdx.x;
  const int r = tid >> 2, cs = (tid & 3) * 16;
  const float* src = W + (size_t)(k0 + r) * Dc + n0 + cs;
  float4 f0 = *(const float4*)(src + 0);
  float4 f1 = *(const float4*)(src + 4);
  float4 f2 = *(const float4*)(src + 8);
  float4 f3 = *(const float4*)(src + 12);
#pragma unroll
  for (int j = 0; j < 4; ++j) {
    tile[r][cs + j] = ((const float*)&f0)[j];
    tile[r][cs + 4 + j] = ((const float*)&f1)[j];
    tile[r][cs + 8 + j] = ((const float*)&f2)[j];
    tile[r][cs + 12 + j] = ((const float*)&f3)[j];
  }
  __syncthreads();
  bf16x8 o0, o1;
#pragma unroll
  for (int j = 0; j < 8; ++j) {
    o0[j] = (__bf16)tile[cs + j][r];
    o1[j] = (__bf16)tile[cs + 8 + j][r];
  }
  __bf16* dst = out + (size_t)(n0 + r) * Dc + k0 + cs;
  *(bf16x8*)(dst) = o0;
  *(bf16x8*)(dst + 8) = o1;
}

// ---------------- Kernel 2: fused QKV GEMM (256N x 128M, fragment-order LDS)
// Same 1-barrier/3-buffer schedule as R11, but A/B staged into LDS in MFMA
// FRAGMENT ORDER via per-lane global-source permutation:
//   A slot s: wr=s>>8, i=(s>>6)&3, l=s&63 holds
//     A[m0 + wr*64+i*16+(l&15)][k0+(l>>4)*8 ..+7]
//   B slot s (2 passes): wc=s>>8, j=(s>>6)&3, l=s&63 holds
//     Wt[n0 + wc*64+j*16+(l&15)][k0+(l>>4)*8 ..+7]
// Global address SET per wave is unchanged (16 x 64B row segments; BK=32 means
// a row's span is 64B either way) -> coalescing unchanged. LDS reads become
// base + frag*1024B + lane*16B: linear, ZERO bank conflicts (R7 counter showed
// 6.29M conflicts with the old 4-chunk XOR: rows 4 apart = 256B = same banks).
// NOTE: no min-waves in __launch_bounds__ (R7 lesson: (512,6) spilled acc).
__global__ __launch_bounds__(512) void qkv_gemm_kernel(
    const __bf16* __restrict__ A, const __bf16* __restrict__ Wt,
    const float* __restrict__ bq, const float* __restrict__ bk,
    const float* __restrict__ bv,
    __bf16* __restrict__ Qo, __bf16* __restrict__ Kf, __bf16* __restrict__ Vf) {
  const int wg = (blockIdx.x & 7) * 96 + (blockIdx.x >> 3);
  const int nn = wg >> 6;            // 0..11 (256-col panel)
  const int mm = wg & 63;            // 0..63 (128-row panel)
  const int m0 = mm * 128;
  const int n0 = nn * 256;           // global col in [0,3072)
  const int w = n0 >> 10;            // 0=Q,1=K,2=V
  const int nbase = n0 & 1023;

  const float* bias = (w == 0) ? bq : (w == 1 ? bk : bv);

  __shared__ __attribute__((aligned(16))) __bf16 Asm[3][4096];   // [wr][i][lane]x8
  __shared__ __attribute__((aligned(16))) __bf16 Bsm[3][8192];   // [wc][j][lane]x8

  const int tid = threadIdx.x, lane = tid & 63, wid = tid >> 6;
  const int wr = wid >> 2, wc = wid & 3;   // 2M x 4N waves
  const int lg = lane >> 4, li = lane & 15;

  f32x4 acc[4][4] = {};

  // 3 gloads/thread per stage; fragment-order source permutation.
  auto stage = [&](int buf, int kt) {
    const int k0 = kt * 32;
    {
      const int l = tid & 63;
      const int row = ((tid >> 8) * 64) + (((tid >> 6) & 3) * 16) + (l & 15);
      const int col = k0 + ((l >> 4) * 8);
      gload_lds16(A + (size_t)(m0 + row) * Dc + col, &Asm[buf][wid * 512]);
    }
#pragma unroll
    for (int p = 0; p < 2; ++p) {
      const int s = p * 512 + tid;
      const int l = s & 63;
      const int row = ((s >> 8) * 64) + (((s >> 6) & 3) * 16) + (l & 15);
      const int col = k0 + ((l >> 4) * 8);
      gload_lds16(Wt + (size_t)(n0 + row) * Dc + col,
                  &Bsm[buf][p * 4096 + wid * 512]);
    }
  };

  // linear fragment reads: frag i at (wr*4+i)*512 + lane*8
  const int aoff = wr * 2048 + lane * 8;
  const int boff = wc * 2048 + lane * 8;

  stage(0, 0);
  stage(1, 1);
  for (int ks = 0; ks < 32; ++ks) {
    asm volatile("s_waitcnt vmcnt(3)" ::: "memory");  // tile ks landed
    __builtin_amdgcn_sched_barrier(0);
    __builtin_amdgcn_s_barrier();
    __builtin_amdgcn_sched_barrier(0);
    {
      const int tn = (ks + 2 < 32) ? ks + 2 : 31;
      stage((ks + 2) % 3, tn);
    }
    const __bf16* Ab = &Asm[ks % 3][0] + aoff;
    const __bf16* Bb = &Bsm[ks % 3][0] + boff;
    bf16x8 af[4], bfr[4];
#pragma unroll
    for (int i = 0; i < 4; ++i) af[i] = *(const bf16x8*)(Ab + i * 512);
#pragma unroll
    for (int j = 0; j < 4; ++j) bfr[j] = *(const bf16x8*)(Bb + j * 512);
    __builtin_amdgcn_s_setprio(1);
#pragma unroll
    for (int i = 0; i < 4; ++i)
#pragma unroll
      for (int j = 0; j < 4; ++j)
        acc[i][j] = mfma16(af[i], bfr[j], acc[i][j]);
    __builtin_amdgcn_s_setprio(0);
  }

  if (w == 0) {
    const float scl = 0.125f * LOG2E;
#pragma unroll
    for (int i = 0; i < 4; ++i) {
#pragma unroll
      for (int j = 0; j < 4; ++j) {
        const int n = nbase + wc * 64 + j * 16 + li;
        const float bb = bias[n];
        const int h = n >> 6, hd = n & 63;
#pragma unroll
        for (int r = 0; r < 4; ++r) {
          const int m = m0 + wr * 64 + i * 16 + lg * 4 + r;
          const int b = m >> 11, s = m & 2047;
          Qo[(((size_t)b * Hc + h) * Sc + s) * HDc + hd] =
              (__bf16)((acc[i][j][r] + bb) * scl);
        }
      }
    }
  } else if (w == 1) {
#pragma unroll
    for (int j = 0; j < 4; ++j) {
      const int n = nbase + wc * 64 + j * 16 + li;
      const float bb = bias[n];
      const int h = n >> 6, hd = n & 63;
      const int c = hd >> 4, shi = (hd >> 3) & 1, j8 = hd & 7;
#pragma unroll
      for (int i = 0; i < 4; ++i) {
#pragma unroll
        for (int r = 0; r < 4; ++r) {
          const int m = m0 + wr * 64 + i * 16 + lg * 4 + r;
          const int b = m >> 11, s = m & 2047;
          const int bh = b * Hc + h;
          const int t = s >> 6, kt = s & 63;
          const int slot = (kt >> 5) * 256 + c * 64 + shi * 32 + (kt & 31);
          Kf[((size_t)(bh * 32 + t)) * 4096 + slot * 8 + j8] =
              (__bf16)(acc[i][j][r] + bb);
        }
      }
    }
  } else {
#pragma unroll
    for (int i = 0; i < 4; ++i) {
      const int mbase = m0 + wr * 64 + i * 16 + lg * 4;
      const int b = mbase >> 11, sk = mbase & 2047;
      const int t = sk >> 6, kt = sk & 63;
      const int kc = kt >> 4, shi = (kt >> 3) & 1, j0 = kt & 7;  // j0 in {0,4}
#pragma unroll
      for (int j = 0; j < 4; ++j) {
        const int n = nbase + wc * 64 + j * 16 + li;
        const float bb = bias[n];
        const int h = n >> 6, hd = n & 63;
        const int nb = hd >> 5, sqr = hd & 31;
        const int bh = b * Hc + h;
        const int slot = kc * 128 + nb * 64 + shi * 32 + sqr;
        bf16x4 o;
#pragma unroll
        for (int r = 0; r < 4; ++r) o[r] = (__bf16)(acc[i][j][r] + bb);
        *(bf16x4*)&Vf[((size_t)(bh * 32 + t)) * 4096 + slot * 8 + j0] = o;
      }
    }
  }
}

// ---------------- Kernel 3: attention (R11 version, reverted from R12) -----
// 8 waves x 32 q-rows, shared K/V LDS, 3 buffers, 1-ahead, 1 barrier/iter.
// R12's 2-q-sets/wave variant regressed (VGPR 164, occupancy halved,
// 87->117us): attn is latency-bound and needs waves, not per-wave work.
__global__ __launch_bounds__(512) void attn_kernel(
    const __bf16* __restrict__ Q, const __bf16* __restrict__ Kf,
    const __bf16* __restrict__ Vf, const float* __restrict__ mkx,
    float* __restrict__ out) {
  const int idx = blockIdx.x;            // 0..511
  const int bh = (idx & 7) | (((idx >> 3) & 7) << 3);
  const int qt = idx >> 6;               // 0..7
  const int b = bh >> 4, h = bh & 15;
  const __bf16* qb = Q + (size_t)bh * Sc * HDc;
  const __bf16* kfb = Kf + (size_t)bh * 32 * 4096;
  const __bf16* vfb = Vf + (size_t)bh * 32 * 4096;
  const float* mb = mkx + (size_t)b * Sc;

  const int tid = threadIdx.x, lane = tid & 63, wid = tid >> 6;  // wid 0..7
  const int hi = lane >> 5, qr = lane & 31;

  __shared__ __attribute__((aligned(16))) __bf16 Ksm[3][4096];
  __shared__ __attribute__((aligned(16))) __bf16 Vsm[3][4096];
  __shared__ __attribute__((aligned(16))) float Msm[3][64];

  const int q0 = qt * 256 + wid * 32;

  bf16x8 qf[4];
#pragma unroll
  for (int c = 0; c < 4; ++c)
    qf[c] = *(const bf16x8*)(qb + (size_t)(q0 + qr) * HDc + c * 16 + hi * 8);

  bf16x8 onesv;
#pragma unroll
  for (int j = 0; j < 8; ++j) onesv[j] = (__bf16)1.0f;

  f32x16 oacc[2] = {};
  f32x16 lacc = {};
  f32x16 sA[2], sB[2];

  // exactly 3 vmem ops per wave per stage
  auto stage = [&](int buf, int t) {
    const size_t tb = (size_t)t * 4096;
    gload_lds16(kfb + tb + (size_t)tid * 8, &Ksm[buf][wid * 512]);
    gload_lds16(vfb + tb + (size_t)tid * 8, &Vsm[buf][wid * 512]);
    gload_lds4(mb + t * 64 + lane, &Msm[buf][0]);
  };

  auto qk = [&](int buf, f32x16 (&s)[2]) {
    const __bf16* Kb = &Ksm[buf][0] + lane * 8;
    const float* Mb = &Msm[buf][0];
#pragma unroll
    for (int kb2 = 0; kb2 < 2; ++kb2) {
#pragma unroll
      for (int g = 0; g < 4; ++g) {
        const float4 m4 = *(const float4*)&Mb[kb2 * 32 + g * 8 + hi * 4];
#pragma unroll
        for (int e = 0; e < 4; ++e) s[kb2][g * 4 + e] = ((const float*)&m4)[e];
      }
    }
    __builtin_amdgcn_s_setprio(1);
#pragma unroll
    for (int kb2 = 0; kb2 < 2; ++kb2) {
#pragma unroll
      for (int c = 0; c < 4; ++c) {
        const bf16x8 kf = *(const bf16x8*)(Kb + (kb2 * 4 + c) * 512);
        s[kb2] = mfma32(kf, qf[c], s[kb2]);
      }
    }
    __builtin_amdgcn_s_setprio(0);
  };

  auto softpv = [&](int buf, f32x16 (&s)[2]) {
    const __bf16* Vb = &Vsm[buf][0] + lane * 8;
    bf16x8 pa[4];
#pragma unroll
    for (int kb2 = 0; kb2 < 2; ++kb2) {
      uint32_t wv[8];
#pragma unroll
      for (int j = 0; j < 8; ++j)
        wv[j] = cvtpk_bf16(__builtin_amdgcn_exp2f(s[kb2][2 * j]),
                           __builtin_amdgcn_exp2f(s[kb2][2 * j + 1]));
#pragma unroll
      for (int cc = 0; cc < 2; ++cc) {
        i32x2_t s02 = __builtin_amdgcn_permlane32_swap(
            (int)wv[cc * 4 + 0], (int)wv[cc * 4 + 2], false, false);
        i32x2_t s13 = __builtin_amdgcn_permlane32_swap(
            (int)wv[cc * 4 + 1], (int)wv[cc * 4 + 3], false, false);
        union { uint32_t u[4]; bf16x8 v; } af;
        af.u[0] = (uint32_t)s02[0];
        af.u[1] = (uint32_t)s13[0];
        af.u[2] = (uint32_t)s02[1];
        af.u[3] = (uint32_t)s13[1];
        pa[kb2 * 2 + cc] = af.v;
      }
    }
    __builtin_amdgcn_s_setprio(1);
#pragma unroll
    for (int kc = 0; kc < 4; ++kc) {
      lacc = mfma32(pa[kc], onesv, lacc);
#pragma unroll
      for (int nb = 0; nb < 2; ++nb) {
        const bf16x8 vf = *(const bf16x8*)(Vb + (kc * 2 + nb) * 512);
        oacc[nb] = mfma32(pa[kc], vf, oacc[nb]);
      }
    }
    __builtin_amdgcn_s_setprio(0);
  };

  const int NT = Sc / 64;  // 32

  stage(0, 0);
  stage(1, 1);
  __builtin_amdgcn_sched_barrier(0);
  asm volatile("s_waitcnt vmcnt(3)" ::: "memory");  // tile 0 landed (mine)
  __builtin_amdgcn_s_barrier();                     // => all waves' tile 0
  __builtin_amdgcn_sched_barrier(0);
  qk(0, sA);

  // iter t: bufs PB=t%3 (softpv), QB=(t+1)%3 (qk), SB=(t+2)%3 (stage)
#define ITER(T, PB, QB, SB, CUR, NXT)                                   \
  {                                                                     \
    const int t_ = (T);                                                 \
    const int tn_ = (t_ + 2 < NT) ? t_ + 2 : NT - 1;                    \
    asm volatile("s_waitcnt vmcnt(0)" ::: "memory");                    \
    __builtin_amdgcn_sched_barrier(0);                                  \
    __builtin_amdgcn_s_barrier();                                       \
    __builtin_amdgcn_sched_barrier(0);                                  \
    stage(SB, tn_);                                                     \
    qk(QB, NXT);                                                        \
    softpv(PB, CUR);                                                    \
  }

  for (int t6 = 0; t6 < 30; t6 += 6) {
    ITER(t6 + 0, 0, 1, 2, sA, sB);
    ITER(t6 + 1, 1, 2, 0, sB, sA);
    ITER(t6 + 2, 2, 0, 1, sA, sB);
    ITER(t6 + 3, 0, 1, 2, sB, sA);
    ITER(t6 + 4, 1, 2, 0, sA, sB);
    ITER(t6 + 5, 2, 0, 1, sB, sA);
  }
  ITER(30, 0, 1, 2, sA, sB);
  ITER(31, 1, 2, 0, sB, sA);
#undef ITER

  float inv[16];
#pragma unroll
  for (int r = 0; r < 16; ++r) inv[r] = __builtin_amdgcn_rcpf(lacc[r]);
#pragma unroll
  for (int nb = 0; nb < 2; ++nb) {
#pragma unroll
    for (int r = 0; r < 16; ++r) {
      const int row = (r & 3) + 8 * (r >> 2) + 4 * hi;
      const int qg = q0 + row;
      out[((size_t)b * Sc + qg) * Dc + h * HDc + nb * 32 + qr] =
          oacc[nb][r] * inv[r];
    }
  }
}

// ---------------- launch ----------------
extern "C" void kernel_launch(void* const* d_in, const int* in_sizes, int n_in,
                              void* d_out, int out_size, void* d_ws,
                              size_t ws_size, hipStream_t stream) {
  const float* hs = (const float*)d_in[0];
  const float* mask = (const float*)d_in[1];
  const float* Wq = (const float*)d_in[2];
  const float* bq = (const float*)d_in[3];
  const float* Wk = (const float*)d_in[4];
  const float* bk = (const float*)d_in[5];
  const float* Wv = (const float*)d_in[6];
  const float* bv = (const float*)d_in[7];
  float* out = (float*)d_out;

  char* ws = (char*)d_ws;
  const size_t qkv_bytes = (size_t)Bc * Hc * Sc * HDc * 2;  // 16.78 MB
  __bf16* Wt = (__bf16*)ws;                                 // 6 MB
  __bf16* Ah = (__bf16*)(ws + 6291456);
  __bf16* Q = (__bf16*)(ws + 6291456 + qkv_bytes);
  __bf16* Kf = (__bf16*)(ws + 6291456 + 2 * qkv_bytes);
  __bf16* Vf = (__bf16*)(ws + 6291456 + 3 * qkv_bytes);
  float* mkx = (float*)(ws + 6291456 + 4 * qkv_bytes);      // 32 KB

  maskscale_kernel<<<32, 256, 0, stream>>>(mask, mkx);
  hs2bf_kernel<<<4096, 256, 0, stream>>>(hs, Ah);
  wtrans_kernel<<<dim3(16, 16, 3), 256, 0, stream>>>(Wq, Wk, Wv, Wt);
  qkv_gemm_kernel<<<768, 512, 0, stream>>>(Ah, Wt, bq, bk, bv, Q, Kf, Vf);
  attn_kernel<<<512, 512, 0, stream>>>(Q, Kf, Vf, mkx, out);
}

// Round 14
// 168.583 us; speedup vs baseline: 1.1824x; 1.1692x over previous
//
#include <hip/hip_runtime.h>
#include <hip/hip_bf16.h>
#include <stdint.h>

#define Bc 4
#define Sc 2048
#define Dc 1024
#define Hc 16
#define HDc 64
#define LOG2E 1.44269504088896f

typedef __attribute__((ext_vector_type(8))) __bf16 bf16x8;
typedef __attribute__((ext_vector_type(4))) __bf16 bf16x4;
typedef __attribute__((ext_vector_type(4))) float f32x4;
typedef __attribute__((ext_vector_type(16))) float f32x16;
typedef __attribute__((ext_vector_type(2))) int i32x2_t;

__device__ __forceinline__ f32x4 mfma16(bf16x8 a, bf16x8 b, f32x4 c) {
  return __builtin_amdgcn_mfma_f32_16x16x32_bf16(a, b, c, 0, 0, 0);
}
__device__ __forceinline__ f32x16 mfma32(bf16x8 a, bf16x8 b, f32x16 c) {
  return __builtin_amdgcn_mfma_f32_32x32x16_bf16(a, b, c, 0, 0, 0);
}
__device__ __forceinline__ uint32_t cvtpk_bf16(float lo, float hi) {
  uint32_t r;
  asm("v_cvt_pk_bf16_f32 %0, %1, %2" : "=v"(r) : "v"(lo), "v"(hi));
  return r;
}
__device__ __forceinline__ void gload_lds16(const void* g, void* l) {
  __builtin_amdgcn_global_load_lds(
      (const __attribute__((address_space(1))) void*)g,
      (__attribute__((address_space(3))) void*)l, 16, 0, 0);
}
__device__ __forceinline__ void gload_lds4(const void* g, void* l) {
  __builtin_amdgcn_global_load_lds(
      (const __attribute__((address_space(1))) void*)g,
      (__attribute__((address_space(3))) void*)l, 4, 0, 0);
}

// ---------------- Kernel 0: fused prep (maskscale | hs2bf | wtrans) --------
// One launch, blockIdx-range dispatch (all 3 jobs independent; branching is
// block-uniform so the wtrans __syncthreads is safe).
//   [0,32)        : mkx = mask * log2e
//   [32,4128)     : Ah = (bf16) hs
//   [4128,4896)   : Wt[w][n][k] = (bf16) W[w][k][n]
__global__ __launch_bounds__(256) void prep_kernel(
    const float* __restrict__ hs, const float* __restrict__ mask,
    const float* __restrict__ Wq, const float* __restrict__ Wk,
    const float* __restrict__ Wv, __bf16* __restrict__ Ah,
    float* __restrict__ mkx, __bf16* __restrict__ Wt) {
  __shared__ float tile[64][65];
  const int bid = blockIdx.x;
  const int tid = threadIdx.x;
  if (bid < 32) {
    const int i = bid * 256 + tid;
    mkx[i] = mask[i] * LOG2E;
  } else if (bid < 4128) {
    const size_t i = ((size_t)(bid - 32) * 256 + tid) * 8;
    float4 f0 = *(const float4*)(hs + i);
    float4 f1 = *(const float4*)(hs + i + 4);
    bf16x8 o;
    o[0] = (__bf16)f0.x; o[1] = (__bf16)f0.y; o[2] = (__bf16)f0.z; o[3] = (__bf16)f0.w;
    o[4] = (__bf16)f1.x; o[5] = (__bf16)f1.y; o[6] = (__bf16)f1.z; o[7] = (__bf16)f1.w;
    *(bf16x8*)(Ah + i) = o;
  } else {
    const int u = bid - 4128;
    const int w = u >> 8;            // 0..2
    const int rem = u & 255;
    const int n0 = (rem & 15) * 64, k0 = (rem >> 4) * 64;
    const float* W = (w == 0) ? Wq : (w == 1 ? Wk : Wv);
    __bf16* out = Wt + (size_t)w * Dc * Dc;
    const int r = tid >> 2, cs = (tid & 3) * 16;
    const float* src = W + (size_t)(k0 + r) * Dc + n0 + cs;
    float4 f0 = *(const float4*)(src + 0);
    float4 f1 = *(const float4*)(src + 4);
    float4 f2 = *(const float4*)(src + 8);
    float4 f3 = *(const float4*)(src + 12);
#pragma unroll
    for (int j = 0; j < 4; ++j) {
      tile[r][cs + j] = ((const float*)&f0)[j];
      tile[r][cs + 4 + j] = ((const float*)&f1)[j];
      tile[r][cs + 8 + j] = ((const float*)&f2)[j];
      tile[r][cs + 12 + j] = ((const float*)&f3)[j];
    }
    __syncthreads();
    bf16x8 o0, o1;
#pragma unroll
    for (int j = 0; j < 8; ++j) {
      o0[j] = (__bf16)tile[cs + j][r];
      o1[j] = (__bf16)tile[cs + 8 + j][r];
    }
    __bf16* dst = out + (size_t)(n0 + r) * Dc + k0 + cs;
    *(bf16x8*)(dst) = o0;
    *(bf16x8*)(dst + 8) = o1;
  }
}

// ---------------- Kernel 2: fused QKV GEMM (R11/R12 version, reverted) -----
// 256N x 128M tile, 8 waves, BK=32, 3-buffer 1-barrier, counted vmcnt(3),
// XOR-chunk LDS swizzle with SOURCE-side pre-swizzle (coalescing-preserving:
// 4 consecutive lanes read one row's 64B). R13's fragment-order staging
// permuted the lane->address map and broke VMEM coalescing (65 -> 109us):
// global-side coalescing dominates LDS bank conflicts for HBM/L3-fed staging.
// NOTE: no min-waves in __launch_bounds__ (R7 lesson: (512,6) spilled acc).
__global__ __launch_bounds__(512) void qkv_gemm_kernel(
    const __bf16* __restrict__ A, const __bf16* __restrict__ Wt,
    const float* __restrict__ bq, const float* __restrict__ bk,
    const float* __restrict__ bv,
    __bf16* __restrict__ Qo, __bf16* __restrict__ Kf, __bf16* __restrict__ Vf) {
  const int wg = (blockIdx.x & 7) * 96 + (blockIdx.x >> 3);
  const int nn = wg >> 6;            // 0..11 (256-col panel)
  const int mm = wg & 63;            // 0..63 (128-row panel)
  const int m0 = mm * 128;
  const int n0 = nn * 256;           // global col in [0,3072)
  const int w = n0 >> 10;            // 0=Q,1=K,2=V
  const int nbase = n0 & 1023;

  const float* bias = (w == 0) ? bq : (w == 1 ? bk : bv);

  __shared__ __attribute__((aligned(16))) __bf16 Asm[3][4096];   // 128x32
  __shared__ __attribute__((aligned(16))) __bf16 Bsm[3][8192];   // 256x32

  const int tid = threadIdx.x, lane = tid & 63, wid = tid >> 6;
  const int wr = wid >> 2, wc = wid & 3;   // 2M x 4N waves
  const int lg = lane >> 4, li = lane & 15;

  f32x4 acc[4][4] = {};

  auto stage = [&](int buf, int kt) {
    const int k0 = kt * 32;
    {
      const int row = tid >> 2;
      const int sc = (tid & 3) ^ (row & 3);
      gload_lds16(A + (size_t)(m0 + row) * Dc + k0 + sc * 8,
                  &Asm[buf][wid * 512]);
    }
#pragma unroll
    for (int p = 0; p < 2; ++p) {
      const int row = p * 128 + (tid >> 2);
      const int sc = (tid & 3) ^ (row & 3);
      gload_lds16(Wt + (size_t)(n0 + row) * Dc + k0 + sc * 8,
                  &Bsm[buf][p * 4096 + wid * 512]);
    }
  };

  const int aoff = (wr * 64 + li) * 32 + ((lg ^ (li & 3)) * 8);
  const int boff = (wc * 64 + li) * 32 + ((lg ^ (li & 3)) * 8);

  stage(0, 0);
  stage(1, 1);
  for (int ks = 0; ks < 32; ++ks) {
    asm volatile("s_waitcnt vmcnt(3)" ::: "memory");  // tile ks landed
    __builtin_amdgcn_sched_barrier(0);
    __builtin_amdgcn_s_barrier();
    __builtin_amdgcn_sched_barrier(0);
    {
      const int tn = (ks + 2 < 32) ? ks + 2 : 31;
      stage((ks + 2) % 3, tn);
    }
    const __bf16* Ab = &Asm[ks % 3][0] + aoff;
    const __bf16* Bb = &Bsm[ks % 3][0] + boff;
    bf16x8 af[4], bfr[4];
#pragma unroll
    for (int i = 0; i < 4; ++i) af[i] = *(const bf16x8*)(Ab + i * 512);
#pragma unroll
    for (int j = 0; j < 4; ++j) bfr[j] = *(const bf16x8*)(Bb + j * 512);
    __builtin_amdgcn_s_setprio(1);
#pragma unroll
    for (int i = 0; i < 4; ++i)
#pragma unroll
      for (int j = 0; j < 4; ++j)
        acc[i][j] = mfma16(af[i], bfr[j], acc[i][j]);
    __builtin_amdgcn_s_setprio(0);
  }

  if (w == 0) {
    const float scl = 0.125f * LOG2E;
#pragma unroll
    for (int i = 0; i < 4; ++i) {
#pragma unroll
      for (int j = 0; j < 4; ++j) {
        const int n = nbase + wc * 64 + j * 16 + li;
        const float bb = bias[n];
        const int h = n >> 6, hd = n & 63;
#pragma unroll
        for (int r = 0; r < 4; ++r) {
          const int m = m0 + wr * 64 + i * 16 + lg * 4 + r;
          const int b = m >> 11, s = m & 2047;
          Qo[(((size_t)b * Hc + h) * Sc + s) * HDc + hd] =
              (__bf16)((acc[i][j][r] + bb) * scl);
        }
      }
    }
  } else if (w == 1) {
#pragma unroll
    for (int j = 0; j < 4; ++j) {
      const int n = nbase + wc * 64 + j * 16 + li;
      const float bb = bias[n];
      const int h = n >> 6, hd = n & 63;
      const int c = hd >> 4, shi = (hd >> 3) & 1, j8 = hd & 7;
#pragma unroll
      for (int i = 0; i < 4; ++i) {
#pragma unroll
        for (int r = 0; r < 4; ++r) {
          const int m = m0 + wr * 64 + i * 16 + lg * 4 + r;
          const int b = m >> 11, s = m & 2047;
          const int bh = b * Hc + h;
          const int t = s >> 6, kt = s & 63;
          const int slot = (kt >> 5) * 256 + c * 64 + shi * 32 + (kt & 31);
          Kf[((size_t)(bh * 32 + t)) * 4096 + slot * 8 + j8] =
              (__bf16)(acc[i][j][r] + bb);
        }
      }
    }
  } else {
#pragma unroll
    for (int i = 0; i < 4; ++i) {
      const int mbase = m0 + wr * 64 + i * 16 + lg * 4;
      const int b = mbase >> 11, sk = mbase & 2047;
      const int t = sk >> 6, kt = sk & 63;
      const int kc = kt >> 4, shi = (kt >> 3) & 1, j0 = kt & 7;  // j0 in {0,4}
#pragma unroll
      for (int j = 0; j < 4; ++j) {
        const int n = nbase + wc * 64 + j * 16 + li;
        const float bb = bias[n];
        const int h = n >> 6, hd = n & 63;
        const int nb = hd >> 5, sqr = hd & 31;
        const int bh = b * Hc + h;
        const int slot = kc * 128 + nb * 64 + shi * 32 + sqr;
        bf16x4 o;
#pragma unroll
        for (int r = 0; r < 4; ++r) o[r] = (__bf16)(acc[i][j][r] + bb);
        *(bf16x4*)&Vf[((size_t)(bh * 32 + t)) * 4096 + slot * 8 + j0] = o;
      }
    }
  }
}

// ---------------- Kernel 3: attention (R11 version, best known) ------------
// 8 waves x 32 q-rows, shared K/V LDS, 3 buffers, 1-ahead, 1 barrier/iter.
__global__ __launch_bounds__(512) void attn_kernel(
    const __bf16* __restrict__ Q, const __bf16* __restrict__ Kf,
    const __bf16* __restrict__ Vf, const float* __restrict__ mkx,
    float* __restrict__ out) {
  const int idx = blockIdx.x;            // 0..511
  const int bh = (idx & 7) | (((idx >> 3) & 7) << 3);
  const int qt = idx >> 6;               // 0..7
  const int b = bh >> 4, h = bh & 15;
  const __bf16* qb = Q + (size_t)bh * Sc * HDc;
  const __bf16* kfb = Kf + (size_t)bh * 32 * 4096;
  const __bf16* vfb = Vf + (size_t)bh * 32 * 4096;
  const float* mb = mkx + (size_t)b * Sc;

  const int tid = threadIdx.x, lane = tid & 63, wid = tid >> 6;  // wid 0..7
  const int hi = lane >> 5, qr = lane & 31;

  __shared__ __attribute__((aligned(16))) __bf16 Ksm[3][4096];
  __shared__ __attribute__((aligned(16))) __bf16 Vsm[3][4096];
  __shared__ __attribute__((aligned(16))) float Msm[3][64];

  const int q0 = qt * 256 + wid * 32;

  bf16x8 qf[4];
#pragma unroll
  for (int c = 0; c < 4; ++c)
    qf[c] = *(const bf16x8*)(qb + (size_t)(q0 + qr) * HDc + c * 16 + hi * 8);

  bf16x8 onesv;
#pragma unroll
  for (int j = 0; j < 8; ++j) onesv[j] = (__bf16)1.0f;

  f32x16 oacc[2] = {};
  f32x16 lacc = {};
  f32x16 sA[2], sB[2];

  // exactly 3 vmem ops per wave per stage
  auto stage = [&](int buf, int t) {
    const size_t tb = (size_t)t * 4096;
    gload_lds16(kfb + tb + (size_t)tid * 8, &Ksm[buf][wid * 512]);
    gload_lds16(vfb + tb + (size_t)tid * 8, &Vsm[buf][wid * 512]);
    gload_lds4(mb + t * 64 + lane, &Msm[buf][0]);
  };

  auto qk = [&](int buf, f32x16 (&s)[2]) {
    const __bf16* Kb = &Ksm[buf][0] + lane * 8;
    const float* Mb = &Msm[buf][0];
#pragma unroll
    for (int kb2 = 0; kb2 < 2; ++kb2) {
#pragma unroll
      for (int g = 0; g < 4; ++g) {
        const float4 m4 = *(const float4*)&Mb[kb2 * 32 + g * 8 + hi * 4];
#pragma unroll
        for (int e = 0; e < 4; ++e) s[kb2][g * 4 + e] = ((const float*)&m4)[e];
      }
    }
    __builtin_amdgcn_s_setprio(1);
#pragma unroll
    for (int kb2 = 0; kb2 < 2; ++kb2) {
#pragma unroll
      for (int c = 0; c < 4; ++c) {
        const bf16x8 kf = *(const bf16x8*)(Kb + (kb2 * 4 + c) * 512);
        s[kb2] = mfma32(kf, qf[c], s[kb2]);
      }
    }
    __builtin_amdgcn_s_setprio(0);
  };

  auto softpv = [&](int buf, f32x16 (&s)[2]) {
    const __bf16* Vb = &Vsm[buf][0] + lane * 8;
    bf16x8 pa[4];
#pragma unroll
    for (int kb2 = 0; kb2 < 2; ++kb2) {
      uint32_t wv[8];
#pragma unroll
      for (int j = 0; j < 8; ++j)
        wv[j] = cvtpk_bf16(__builtin_amdgcn_exp2f(s[kb2][2 * j]),
                           __builtin_amdgcn_exp2f(s[kb2][2 * j + 1]));
#pragma unroll
      for (int cc = 0; cc < 2; ++cc) {
        i32x2_t s02 = __builtin_amdgcn_permlane32_swap(
            (int)wv[cc * 4 + 0], (int)wv[cc * 4 + 2], false, false);
        i32x2_t s13 = __builtin_amdgcn_permlane32_swap(
            (int)wv[cc * 4 + 1], (int)wv[cc * 4 + 3], false, false);
        union { uint32_t u[4]; bf16x8 v; } af;
        af.u[0] = (uint32_t)s02[0];
        af.u[1] = (uint32_t)s13[0];
        af.u[2] = (uint32_t)s02[1];
        af.u[3] = (uint32_t)s13[1];
        pa[kb2 * 2 + cc] = af.v;
      }
    }
    __builtin_amdgcn_s_setprio(1);
#pragma unroll
    for (int kc = 0; kc < 4; ++kc) {
      lacc = mfma32(pa[kc], onesv, lacc);
#pragma unroll
      for (int nb = 0; nb < 2; ++nb) {
        const bf16x8 vf = *(const bf16x8*)(Vb + (kc * 2 + nb) * 512);
        oacc[nb] = mfma32(pa[kc], vf, oacc[nb]);
      }
    }
    __builtin_amdgcn_s_setprio(0);
  };

  const int NT = Sc / 64;  // 32

  stage(0, 0);
  stage(1, 1);
  __builtin_amdgcn_sched_barrier(0);
  asm volatile("s_waitcnt vmcnt(3)" ::: "memory");  // tile 0 landed (mine)
  __builtin_amdgcn_s_barrier();                     // => all waves' tile 0
  __builtin_amdgcn_sched_barrier(0);
  qk(0, sA);

  // iter t: bufs PB=t%3 (softpv), QB=(t+1)%3 (qk), SB=(t+2)%3 (stage)
#define ITER(T, PB, QB, SB, CUR, NXT)                                   \
  {                                                                     \
    const int t_ = (T);                                                 \
    const int tn_ = (t_ + 2 < NT) ? t_ + 2 : NT - 1;                    \
    asm volatile("s_waitcnt vmcnt(0)" ::: "memory");                    \
    __builtin_amdgcn_sched_barrier(0);                                  \
    __builtin_amdgcn_s_barrier();                                       \
    __builtin_amdgcn_sched_barrier(0);                                  \
    stage(SB, tn_);                                                     \
    qk(QB, NXT);                                                        \
    softpv(PB, CUR);                                                    \
  }

  for (int t6 = 0; t6 < 30; t6 += 6) {
    ITER(t6 + 0, 0, 1, 2, sA, sB);
    ITER(t6 + 1, 1, 2, 0, sB, sA);
    ITER(t6 + 2, 2, 0, 1, sA, sB);
    ITER(t6 + 3, 0, 1, 2, sB, sA);
    ITER(t6 + 4, 1, 2, 0, sA, sB);
    ITER(t6 + 5, 2, 0, 1, sB, sA);
  }
  ITER(30, 0, 1, 2, sA, sB);
  ITER(31, 1, 2, 0, sB, sA);
#undef ITER

  float inv[16];
#pragma unroll
  for (int r = 0; r < 16; ++r) inv[r] = __builtin_amdgcn_rcpf(lacc[r]);
#pragma unroll
  for (int nb = 0; nb < 2; ++nb) {
#pragma unroll
    for (int r = 0; r < 16; ++r) {
      const int row = (r & 3) + 8 * (r >> 2) + 4 * hi;
      const int qg = q0 + row;
      out[((size_t)b * Sc + qg) * Dc + h * HDc + nb * 32 + qr] =
          oacc[nb][r] * inv[r];
    }
  }
}

// ---------------- launch ----------------
extern "C" void kernel_launch(void* const* d_in, const int* in_sizes, int n_in,
                              void* d_out, int out_size, void* d_ws,
                              size_t ws_size, hipStream_t stream) {
  const float* hs = (const float*)d_in[0];
  const float* mask = (const float*)d_in[1];
  const float* Wq = (const float*)d_in[2];
  const float* bq = (const float*)d_in[3];
  const float* Wk = (const float*)d_in[4];
  const float* bk = (const float*)d_in[5];
  const float* Wv = (const float*)d_in[6];
  const float* bv = (const float*)d_in[7];
  float* out = (float*)d_out;

  char* ws = (char*)d_ws;
  const size_t qkv_bytes = (size_t)Bc * Hc * Sc * HDc * 2;  // 16.78 MB
  __bf16* Wt = (__bf16*)ws;                                 // 6 MB
  __bf16* Ah = (__bf16*)(ws + 6291456);
  __bf16* Q = (__bf16*)(ws + 6291456 + qkv_bytes);
  __bf16* Kf = (__bf16*)(ws + 6291456 + 2 * qkv_bytes);
  __bf16* Vf = (__bf16*)(ws + 6291456 + 3 * qkv_bytes);
  float* mkx = (float*)(ws + 6291456 + 4 * qkv_bytes);      // 32 KB

  prep_kernel<<<4896, 256, 0, stream>>>(hs, mask, Wq, Wk, Wv, Ah, mkx, Wt);
  qkv_gemm_kernel<<<768, 512, 0, stream>>>(Ah, Wt, bq, bk, bv, Q, Kf, Vf);
  attn_kernel<<<512, 512, 0, stream>>>(Q, Kf, Vf, mkx, out);
}